// Round 2
// baseline (206.175 us; speedup 1.0000x reference)
//
#include <hip/hip_runtime.h>

// Problem constants (fixed by setup_inputs): B=256, J=17, H*W=3072.
#define N_TOTAL   (256 * 17 * 3072)       // 13,369,344 elements
#define N_VEC4    (N_TOTAL / 4)           // 3,342,336 float4s
#define NBLOCKS   2048                    // 8 blocks/CU -> 32 waves/CU (max occupancy)
#define BLOCK     256

// Fused weighted-SSE reduction:
//   acc = sum over all elements of tw[b,j]^2 * (o - t)^2, out = 0.5*acc/N.
// Each block computes a partial, atomicAdd's it into ws[0], then bumps a
// counter ws[1]; the last block to finish reads the full sum and writes d_out.
// ws[0..1] are zeroed by an 8-byte hipMemsetAsync before launch (d_ws is
// re-poisoned to 0xAA by the harness before every call).
__global__ __launch_bounds__(BLOCK) void fused_sse_kernel(
    const float* __restrict__ out,
    const float* __restrict__ tgt,
    const float* __restrict__ tw,
    float* __restrict__ ws,            // ws[0] = f32 accumulator, ws[1] = uint counter
    float* __restrict__ loss_out)
{
    const float4* o4 = (const float4*)out;
    const float4* t4 = (const float4*)tgt;

    int tid    = blockIdx.x * BLOCK + threadIdx.x;
    int stride = gridDim.x * BLOCK;

    float acc = 0.0f;
    for (int i = tid; i < N_VEC4; i += stride) {
        float4 o = o4[i];
        float4 t = t4[i];
        float  w = tw[i / 768];          // 3072/4; broadcast within a wave, L1-resident
        float  w2 = w * w;
        float d0 = o.x - t.x;
        float d1 = o.y - t.y;
        float d2 = o.z - t.z;
        float d3 = o.w - t.w;
        acc += w2 * (d0 * d0 + d1 * d1 + d2 * d2 + d3 * d3);
    }

    // wave64 shuffle reduction
    #pragma unroll
    for (int off = 32; off > 0; off >>= 1)
        acc += __shfl_down(acc, off, 64);

    __shared__ float lds[BLOCK / 64];
    int lane = threadIdx.x & 63;
    int wave = threadIdx.x >> 6;
    if (lane == 0) lds[wave] = acc;
    __syncthreads();

    if (threadIdx.x == 0) {
        float s = 0.0f;
        #pragma unroll
        for (int w_i = 0; w_i < BLOCK / 64; ++w_i) s += lds[w_i];

        atomicAdd(&ws[0], s);                       // device-scope by default
        __threadfence();                            // make the add visible before the ticket
        unsigned int* cnt = (unsigned int*)&ws[1];
        unsigned int ticket = atomicAdd(cnt, 1u);
        if (ticket == (unsigned int)gridDim.x - 1u) {
            // All partials are in ws[0]; read with device-scope atomic load.
            float total = __hip_atomic_load(&ws[0], __ATOMIC_RELAXED,
                                            __HIP_MEMORY_SCOPE_AGENT);
            loss_out[0] = 0.5f * total / (float)N_TOTAL;
        }
    }
}

extern "C" void kernel_launch(void* const* d_in, const int* in_sizes, int n_in,
                              void* d_out, int out_size, void* d_ws, size_t ws_size,
                              hipStream_t stream)
{
    const float* output = (const float*)d_in[0];   // [256,17,64,48] f32
    const float* target = (const float*)d_in[1];   // [256,17,64,48] f32
    const float* tw     = (const float*)d_in[2];   // [256,17,1]     f32

    float* ws = (float*)d_ws;

    // Zero the 8-byte accumulator+counter (d_ws is poisoned 0xAA each call).
    hipMemsetAsync(ws, 0, 2 * sizeof(float), stream);

    fused_sse_kernel<<<NBLOCKS, BLOCK, 0, stream>>>(output, target, tw, ws,
                                                    (float*)d_out);
}

// Round 3
// 123.390 us; speedup vs baseline: 1.6709x; 1.6709x over previous
//
#include <hip/hip_runtime.h>

// Problem constants (fixed by setup_inputs): B=256, J=17, H*W=3072.
#define N_TOTAL     (256 * 17 * 3072)     // 13,369,344 elements
#define N_VEC4      (N_TOTAL / 4)         // 3,342,336 float4s
#define BLOCK       256
#define PER_THREAD  8
#define NBLOCKS     1632                  // 1632*256*8 == N_VEC4 exactly -> no bounds checks

// Kernel 1: weighted-SSE partials. Block b owns a contiguous chunk of
// BLOCK*PER_THREAD float4s; iteration k reads a wave-coalesced 4 KB slab
// (lane-contiguous 16 B each). Fully unrolled -> 16 independent
// global_load_dwordx4 in flight per thread. No atomics, no fences.
__global__ __launch_bounds__(BLOCK) void partial_sse_kernel(
    const float* __restrict__ out,
    const float* __restrict__ tgt,
    const float* __restrict__ tw,
    float* __restrict__ partials)
{
    const float4* o4 = (const float4*)out;
    const float4* t4 = (const float4*)tgt;

    const int base = blockIdx.x * (BLOCK * PER_THREAD) + threadIdx.x;

    float acc = 0.0f;
    #pragma unroll
    for (int k = 0; k < PER_THREAD; ++k) {
        const int i = base + k * BLOCK;
        float4 o = o4[i];
        float4 t = t4[i];
        float  w = tw[i / 768];          // float4 idx -> (b,j): 3072/4=768; L1-hot
        float  w2 = w * w;
        float d0 = o.x - t.x;
        float d1 = o.y - t.y;
        float d2 = o.z - t.z;
        float d3 = o.w - t.w;
        acc += w2 * (d0 * d0 + d1 * d1 + d2 * d2 + d3 * d3);
    }

    // wave64 shuffle reduction
    #pragma unroll
    for (int off = 32; off > 0; off >>= 1)
        acc += __shfl_down(acc, off, 64);

    __shared__ float lds[BLOCK / 64];
    const int lane = threadIdx.x & 63;
    const int wave = threadIdx.x >> 6;
    if (lane == 0) lds[wave] = acc;
    __syncthreads();

    if (threadIdx.x == 0) {
        float s = 0.0f;
        #pragma unroll
        for (int w_i = 0; w_i < BLOCK / 64; ++w_i) s += lds[w_i];
        partials[blockIdx.x] = s;
    }
}

// Kernel 2: reduce NBLOCKS partials, scale, write the scalar loss.
__global__ __launch_bounds__(BLOCK) void final_reduce_kernel(
    const float* __restrict__ partials,
    float* __restrict__ loss_out)
{
    float acc = 0.0f;
    for (int i = threadIdx.x; i < NBLOCKS; i += BLOCK)
        acc += partials[i];

    #pragma unroll
    for (int off = 32; off > 0; off >>= 1)
        acc += __shfl_down(acc, off, 64);

    __shared__ float lds[BLOCK / 64];
    const int lane = threadIdx.x & 63;
    const int wave = threadIdx.x >> 6;
    if (lane == 0) lds[wave] = acc;
    __syncthreads();

    if (threadIdx.x == 0) {
        float s = 0.0f;
        #pragma unroll
        for (int w_i = 0; w_i < BLOCK / 64; ++w_i) s += lds[w_i];
        loss_out[0] = 0.5f * s / (float)N_TOTAL;
    }
}

extern "C" void kernel_launch(void* const* d_in, const int* in_sizes, int n_in,
                              void* d_out, int out_size, void* d_ws, size_t ws_size,
                              hipStream_t stream)
{
    const float* output = (const float*)d_in[0];   // [256,17,64,48] f32
    const float* target = (const float*)d_in[1];   // [256,17,64,48] f32
    const float* tw     = (const float*)d_in[2];   // [256,17,1]     f32

    float* partials = (float*)d_ws;                // NBLOCKS floats (6.4 KB)

    partial_sse_kernel<<<NBLOCKS, BLOCK, 0, stream>>>(output, target, tw, partials);
    final_reduce_kernel<<<1, BLOCK, 0, stream>>>(partials, (float*)d_out);
}

// Round 4
// 122.409 us; speedup vs baseline: 1.6843x; 1.0080x over previous
//
#include <hip/hip_runtime.h>

// Problem constants (fixed by setup_inputs): B=256, J=17, H*W=3072.
#define N_TOTAL     (256 * 17 * 3072)     // 13,369,344 elements
#define N_VEC4      (N_TOTAL / 4)         // 3,342,336 float4s
#define BLOCK       256
#define PER_THREAD  17
#define NBLOCKS     768                   // 768*256*17 == N_VEC4 exactly
                                          // 768 = 3 blocks/CU on 256 CUs: zero tail imbalance

// Kernel 1: weighted-SSE partials. Block b owns BLOCK*PER_THREAD = 4352
// consecutive float4s; iteration k reads a wave-coalesced slab (lane-contiguous
// 16 B each). No atomics, no fences, no bounds checks (exact decomposition).
__global__ __launch_bounds__(BLOCK) void partial_sse_kernel(
    const float* __restrict__ out,
    const float* __restrict__ tgt,
    const float* __restrict__ tw,
    float* __restrict__ partials)
{
    const float4* o4 = (const float4*)out;
    const float4* t4 = (const float4*)tgt;

    const int base = blockIdx.x * (BLOCK * PER_THREAD) + threadIdx.x;

    float acc = 0.0f;
    #pragma unroll
    for (int k = 0; k < PER_THREAD; ++k) {
        const int i = base + k * BLOCK;
        float4 o = o4[i];
        float4 t = t4[i];
        float  w = tw[i / 768];          // float4 idx -> (b,j): 3072/4=768; L1-hot
        float  w2 = w * w;
        float d0 = o.x - t.x;
        float d1 = o.y - t.y;
        float d2 = o.z - t.z;
        float d3 = o.w - t.w;
        acc += w2 * (d0 * d0 + d1 * d1 + d2 * d2 + d3 * d3);
    }

    // wave64 shuffle reduction
    #pragma unroll
    for (int off = 32; off > 0; off >>= 1)
        acc += __shfl_down(acc, off, 64);

    __shared__ float lds[BLOCK / 64];
    const int lane = threadIdx.x & 63;
    const int wave = threadIdx.x >> 6;
    if (lane == 0) lds[wave] = acc;
    __syncthreads();

    if (threadIdx.x == 0) {
        float s = 0.0f;
        #pragma unroll
        for (int w_i = 0; w_i < BLOCK / 64; ++w_i) s += lds[w_i];
        partials[blockIdx.x] = s;
    }
}

// Kernel 2: reduce NBLOCKS partials, scale, write the scalar loss.
__global__ __launch_bounds__(BLOCK) void final_reduce_kernel(
    const float* __restrict__ partials,
    float* __restrict__ loss_out)
{
    float acc = 0.0f;
    #pragma unroll
    for (int k = 0; k < NBLOCKS / BLOCK; ++k)      // 768/256 = 3, exact
        acc += partials[k * BLOCK + threadIdx.x];

    #pragma unroll
    for (int off = 32; off > 0; off >>= 1)
        acc += __shfl_down(acc, off, 64);

    __shared__ float lds[BLOCK / 64];
    const int lane = threadIdx.x & 63;
    const int wave = threadIdx.x >> 6;
    if (lane == 0) lds[wave] = acc;
    __syncthreads();

    if (threadIdx.x == 0) {
        float s = 0.0f;
        #pragma unroll
        for (int w_i = 0; w_i < BLOCK / 64; ++w_i) s += lds[w_i];
        loss_out[0] = 0.5f * s / (float)N_TOTAL;
    }
}

extern "C" void kernel_launch(void* const* d_in, const int* in_sizes, int n_in,
                              void* d_out, int out_size, void* d_ws, size_t ws_size,
                              hipStream_t stream)
{
    const float* output = (const float*)d_in[0];   // [256,17,64,48] f32
    const float* target = (const float*)d_in[1];   // [256,17,64,48] f32
    const float* tw     = (const float*)d_in[2];   // [256,17,1]     f32

    float* partials = (float*)d_ws;                // NBLOCKS floats (3 KB)

    partial_sse_kernel<<<NBLOCKS, BLOCK, 0, stream>>>(output, target, tw, partials);
    final_reduce_kernel<<<1, BLOCK, 0, stream>>>(partials, (float*)d_out);
}